// Round 1
// baseline (337.651 us; speedup 1.0000x reference)
//
#include <hip/hip_runtime.h>
#include <stdint.h>

#define Bn 4
#define Sn 2048
#define Hn 1024
#define NHn 16
#define Mn 8192   // Bn*Sn

typedef unsigned short bf_t;
typedef __attribute__((ext_vector_type(8))) short s16x8;
typedef __attribute__((ext_vector_type(4))) short s16x4;
typedef __attribute__((ext_vector_type(8))) unsigned short u16x8;
typedef __attribute__((ext_vector_type(4))) unsigned short u16x4;
typedef __attribute__((ext_vector_type(4))) float f32x4;
typedef __attribute__((ext_vector_type(4))) unsigned int u32x4;
typedef __attribute__((ext_vector_type(2))) unsigned int u32x2;

__device__ __forceinline__ bf_t f2bf(float f) {
  unsigned int u = __float_as_uint(f);
  u += 0x7fffu + ((u >> 16) & 1u);   // RNE
  return (bf_t)(u >> 16);
}

// pack two f32 -> two bf16 (truncation) in one v_perm_b32
__device__ __forceinline__ unsigned pk2(float lo, float hi) {
  return __builtin_amdgcn_perm(__float_as_uint(hi), __float_as_uint(lo), 0x07060302u);
}
__device__ __forceinline__ s16x4 pack4(float a0, float a1, float a2, float a3) {
  u32x2 t;
  t[0] = pk2(a0, a1);
  t[1] = pk2(a2, a3);
  return __builtin_bit_cast(s16x4, t);
}

// K=16 bf16 MFMA: ISA v_mfma_f32_16x16x16_bf16; clang spelling "_1k" (v4i16 ops).
#define MFMA16K16(a, b, c) __builtin_amdgcn_mfma_f32_16x16x16bf16_1k(a, b, c, 0, 0, 0)

#define GLOAD16(gp, lp) __builtin_amdgcn_global_load_lds(              \
    (__attribute__((address_space(1))) void*)(gp),                     \
    (__attribute__((address_space(3))) void*)(lp), 16, 0, 0)

// ------- merged prep: 4 weight transposes + query fp32->bf16 convert -------
// grid dim3(32,32,5), block dim3(32,8).
// z 0..2: Wq/Wk/Wv -> Wt (concat). z==3: Wd -> Wdt. z==4: query -> Xb.
__global__ __launch_bounds__(256)
void prep(const float* __restrict__ Wq, const float* __restrict__ Wk,
          const float* __restrict__ Wv, const float* __restrict__ Wd,
          const float* __restrict__ query,
          bf_t* __restrict__ Wt, bf_t* __restrict__ Wdt, bf_t* __restrict__ Xb) {
  __shared__ float tile[32][33];
  const int z = blockIdx.z;
  const int tx = threadIdx.x;   // 0..31
  const int ty = threadIdx.y;   // 0..7
  if (z == 4) {
    const int bid = blockIdx.y * 32 + blockIdx.x;     // 0..1023
    const int t = ty * 32 + tx;
    const size_t base = (size_t)bid * 8192 + t * 4;
#pragma unroll
    for (int i = 0; i < 8; i++) {
      const f32x4 v = *(const f32x4*)(query + base + i * 1024);
      u16x4 o;
      o[0] = f2bf(v[0]); o[1] = f2bf(v[1]); o[2] = f2bf(v[2]); o[3] = f2bf(v[3]);
      *(u16x4*)(Xb + base + i * 1024) = o;
    }
    return;
  }
  const float* W = (z == 0) ? Wq : (z == 1) ? Wk : (z == 2) ? Wv : Wd;
  bf_t* dst = (z < 3) ? Wt + (size_t)z * Hn * Hn : Wdt;
  const int n0 = blockIdx.x * 32, k0 = blockIdx.y * 32;
#pragma unroll
  for (int i = 0; i < 4; i++)
    tile[ty + i * 8][tx] = W[(size_t)(k0 + ty + i * 8) * Hn + n0 + tx];
  __syncthreads();
#pragma unroll
  for (int i = 0; i < 4; i++) {
    const int nn = ty + i * 8, kk = tx;
    dst[(size_t)(n0 + nn) * Hn + k0 + kk] = f2bf(tile[kk][nn]);
  }
}

// -------- m97-style bf16 GEMM-BT, 128x128 tile, BK=32, dbuf LDS --------
// One barrier per K-iteration: barrier -> prefetch(next) -> compute(cur).
__global__ __launch_bounds__(256, 3)
void gemm_bt(const bf_t* __restrict__ A, const bf_t* __restrict__ Bt,
             const float* __restrict__ b0, const float* __restrict__ b1,
             const float* __restrict__ b2, void* __restrict__ outp,
             int N, int K, int out_bf16)
{
  __shared__ bf_t As[2][4096];
  __shared__ bf_t Bs[2][4096];
  const int tid = threadIdx.x;
  const int wave = tid >> 6, lane = tid & 63;
  const int l15 = lane & 15, quad = lane >> 4;
  const int bm = blockIdx.y * 128, bn = blockIdx.x * 128;
  const int wm = (wave >> 1) * 64, wn = (wave & 1) * 64;
  const int srow = tid >> 2;          // 0..63
  const int scol = (tid & 3) * 8;     // 0..24

  const bf_t* Ag = A + (size_t)(bm + srow) * K + scol;
  const bf_t* Bg = Bt + (size_t)(bn + srow) * K + scol;

  f32x4 acc[4][4] = {};

  // preload iter 0
  GLOAD16(Ag, As[0] + tid * 8);
  GLOAD16(Ag + (size_t)64 * K, As[0] + 2048 + tid * 8);
  GLOAD16(Bg, Bs[0] + tid * 8);
  GLOAD16(Bg + (size_t)64 * K, Bs[0] + 2048 + tid * 8);

  const int nIter = K >> 5;
  for (int i = 0; i < nIter; i++) {
    const int cur = i & 1;
    __syncthreads();
    if (i + 1 < nIter) {
      const int k0 = (i + 1) * 32;
      GLOAD16(Ag + k0, As[cur ^ 1] + tid * 8);
      GLOAD16(Ag + (size_t)64 * K + k0, As[cur ^ 1] + 2048 + tid * 8);
      GLOAD16(Bg + k0, Bs[cur ^ 1] + tid * 8);
      GLOAD16(Bg + (size_t)64 * K + k0, Bs[cur ^ 1] + 2048 + tid * 8);
    }
    s16x8 af[4], bfr[4];
#pragma unroll
    for (int mi = 0; mi < 4; mi++)
      af[mi] = *(const s16x8*)&As[cur][(wm + mi * 16 + l15) * 32 + quad * 8];
#pragma unroll
    for (int ni = 0; ni < 4; ni++)
      bfr[ni] = *(const s16x8*)&Bs[cur][(wn + ni * 16 + l15) * 32 + quad * 8];
#pragma unroll
    for (int mi = 0; mi < 4; mi++)
#pragma unroll
      for (int ni = 0; ni < 4; ni++)
        acc[mi][ni] = __builtin_amdgcn_mfma_f32_16x16x32_bf16(af[mi], bfr[ni], acc[mi][ni], 0, 0, 0);
  }

#pragma unroll
  for (int ni = 0; ni < 4; ni++) {
    const int gn = bn + wn + ni * 16 + l15;
    const float* bp = (gn < 1024) ? b0 : ((gn < 2048) ? b1 : b2);
    const float bias = bp[gn & 1023];
#pragma unroll
    for (int mi = 0; mi < 4; mi++) {
#pragma unroll
      for (int r = 0; r < 4; r++) {
        const int gm = bm + wm + mi * 16 + quad * 4 + r;
        const float v = acc[mi][ni][r] + bias;
        if (out_bf16) ((bf_t*)outp)[(size_t)gm * N + gn] = f2bf(v);
        else          ((float*)outp)[(size_t)gm * N + gn] = v;
      }
    }
  }
}

// -------- merged K/V swizzle (+ mask2 = mask*log2e) in one launch --------
__global__ __launch_bounds__(256)
void kvswz(const bf_t* __restrict__ qkv, bf_t* __restrict__ Kf,
           bf_t* __restrict__ Vf, const float* __restrict__ mask,
           float* __restrict__ mask2) {
  __shared__ u32x4 smbuf[640];   // 10240 B, 16-aligned; overlaid per branch
  const int t = threadIdx.x;
  const int bh = blockIdx.y, b = bh >> 4, h = bh & 15;
  const int k0 = blockIdx.x * 64;

  if (blockIdx.z == 0) {
    bf_t* KT = (bf_t*)smbuf;   // stride 80 el = 160 B
#pragma unroll
    for (int i = 0; i < 2; i++) {
      const int c = t + i * 256;
      const int row = c >> 3, col8 = (c & 7) * 8;
      const u16x8 v = *(const u16x8*)(qkv + (size_t)(b * Sn + k0 + row) * 3072 + 1024 + h * 64 + col8);
      *(u16x8*)&KT[row * 80 + col8] = v;
    }
    __syncthreads();
    bf_t* dst0 = Kf + ((size_t)(bh * 32 + blockIdx.x) * 8) * 512;
#pragma unroll
    for (int i = 0; i < 2; i++) {
      const int p = t + i * 256;
      const int frag = p >> 6, lane = p & 63;
      const int ks = frag >> 1, half = frag & 1;
      const int l15 = lane & 15, quad = lane >> 4;
      const u16x8 v = *(const u16x8*)&KT[(ks * 16 + l15) * 80 + half * 32 + quad * 8];
      *(u16x8*)(dst0 + (size_t)frag * 512 + lane * 8) = v;
    }
  } else {
    unsigned int* P32 = (unsigned int*)smbuf;   // [dv][k-pair], stride 33
    {
      const int kp = t >> 3;           // 0..31 (k-pair)
      const int d0 = (t & 7) * 8;
      const bf_t* p0 = qkv + (size_t)(b * Sn + k0 + 2 * kp) * 3072 + 2048 + h * 64 + d0;
      const u16x8 r0 = *(const u16x8*)p0;
      const u16x8 r1 = *(const u16x8*)(p0 + 3072);
#pragma unroll
      for (int j = 0; j < 8; j++)
        P32[(d0 + j) * 33 + kp] = (unsigned)r0[j] | ((unsigned)r1[j] << 16);
    }
    if (h == 0 && t < 64)
      mask2[b * Sn + k0 + t] = mask[b * Sn + k0 + t] * 1.44269504f;
    __syncthreads();
    bf_t* dst0 = Vf + ((size_t)(bh * 32 + blockIdx.x) * 8) * 512;
#pragma unroll
    for (int i = 0; i < 2; i++) {
      const int p = t + i * 256;
      const int fp = p >> 6, lane = p & 63;
      const int dvblk = fp >> 1, kpair = fp & 1;
      const int l15 = lane & 15, quad = (lane >> 4) & 3;
      const int d = dvblk * 16 + l15;
      const int c = kpair * 16 + quad * 2;
      u32x4 w;
      w[0] = P32[d * 33 + c];
      w[1] = P32[d * 33 + c + 1];
      w[2] = P32[d * 33 + c + 8];
      w[3] = P32[d * 33 + c + 9];
      *(u32x4*)(dst0 + (size_t)fp * 512 + lane * 8) = w;
    }
  }
}

// ---------------- flash attention: dbuf LDS, 4 waves x 128 q, k-tile 64 ----
// One barrier per k-iteration. Mask row staged in LDS so in-loop mask reads
// are ds_read (lgkmcnt) — NO vmcnt pollution of the prefetch (vmcnt is
// in-order: a global mask load after the prefetch would force vmcnt(0) and
// drain it). exp2 via raw v_exp_f32 (no libm guard code). l via ones-MFMA.
__global__ __launch_bounds__(256)
void attn(const bf_t* __restrict__ qkv, const bf_t* __restrict__ Kf,
          const bf_t* __restrict__ Vf, const float* __restrict__ mask2,
          bf_t* __restrict__ ctx)
{
  __shared__ bf_t Ks[2][4096];   // 16 KB
  __shared__ bf_t Vs[2][4096];   // 16 KB
  __shared__ float Ms[2048];     // 8 KB: this batch's mask2 row

  const int tid = threadIdx.x;
  const int wave = tid >> 6, lane = tid & 63;
  const int l15 = lane & 15, quad = lane >> 4;
  const int idx = blockIdx.x;
  const int bh = idx & 63, b = bh >> 4, h = bh & 15;
  const int q0 = (idx >> 6) * 128;

  // stage mask2 row into LDS (one-time; before prefetch in program order)
  {
    const float* m2row = mask2 + (size_t)b * Sn;
    const f32x4 m0 = *(const f32x4*)(m2row + tid * 8);
    const f32x4 m1 = *(const f32x4*)(m2row + tid * 8 + 4);
    *(f32x4*)&Ms[tid * 8] = m0;
    *(f32x4*)&Ms[tid * 8 + 4] = m1;
  }

  // Q as x32 B-operand: lane&15 = q-row, d = quad*8+j. 2 q-frags per wave.
  s16x8 aq[2][2];
#pragma unroll
  for (int qf = 0; qf < 2; qf++) {
    const bf_t* qp = qkv + (size_t)(b * Sn + q0 + wave * 32 + qf * 16 + l15) * 3072 + h * 64;
    aq[qf][0] = *(const s16x8*)(qp + quad * 8);
    aq[qf][1] = *(const s16x8*)(qp + 32 + quad * 8);
  }

  f32x4 lacc[2] = {};   // l via ones-MFMA; every reg holds the full row-sum
  f32x4 o[2][4] = {};   // O^T: [qf][dvblk], lane: q=l15, dv=dvblk*16+quad*4+r
  const s16x4 ONES = {16256, 16256, 16256, 16256};   // bf16 1.0 x4

  const bf_t* kb = Kf + (size_t)bh * 32 * 4096;
  const bf_t* vb = Vf + (size_t)bh * 32 * 4096;

  const float C1 = 0.125f * 1.44269504f;   // (1/sqrt(64)) * log2(e)

  // preload tile 0 into buffer 0
#pragma unroll
  for (int c = 0; c < 2; c++) {
    GLOAD16(kb + c * 2048 + tid * 8, Ks[0] + c * 2048 + tid * 8);
    GLOAD16(vb + c * 2048 + tid * 8, Vs[0] + c * 2048 + tid * 8);
  }

  for (int it = 0; it < 32; ++it) {
    const int cur = it & 1;
    __syncthreads();   // waits prefetch of buf[cur] + prior reads of buf[cur^1]
    if (it < 31) {
      const bf_t* kn = kb + (size_t)(it + 1) * 4096;
      const bf_t* vn = vb + (size_t)(it + 1) * 4096;
#pragma unroll
      for (int c = 0; c < 2; c++) {
        GLOAD16(kn + c * 2048 + tid * 8, Ks[cur ^ 1] + c * 2048 + tid * 8);
        GLOAD16(vn + c * 2048 + tid * 8, Vs[cur ^ 1] + c * 2048 + tid * 8);
      }
    }

    // S^T = K·Q^T (x32, A=K frag, B=Q frag) -> p = exp2(s*C1 + mk2)
    s16x4 pb[2][4];
#pragma unroll
    for (int e = 0; e < 4; e++) {
      const s16x8 k0f = *(const s16x8*)&Ks[cur][(e * 2 + 0) * 512 + lane * 8];
      const s16x8 k1f = *(const s16x8*)&Ks[cur][(e * 2 + 1) * 512 + lane * 8];
      const f32x4 mk2 = *(const f32x4*)&Ms[it * 64 + e * 16 + quad * 4];
#pragma unroll
      for (int qf = 0; qf < 2; qf++) {
        f32x4 acc = {};
        acc = __builtin_amdgcn_mfma_f32_16x16x32_bf16(k0f, aq[qf][0], acc, 0, 0, 0);
        acc = __builtin_amdgcn_mfma_f32_16x16x32_bf16(k1f, aq[qf][1], acc, 0, 0, 0);
        const float p0 = __builtin_amdgcn_exp2f(fmaf(acc[0], C1, mk2[0]));
        const float p1 = __builtin_amdgcn_exp2f(fmaf(acc[1], C1, mk2[1]));
        const float p2 = __builtin_amdgcn_exp2f(fmaf(acc[2], C1, mk2[2]));
        const float p3 = __builtin_amdgcn_exp2f(fmaf(acc[3], C1, mk2[3]));
        pb[qf][e] = pack4(p0, p1, p2, p3);
        lacc[qf] = MFMA16K16(ONES, pb[qf][e], lacc[qf]);
      }
    }

    // O^T += V^T·P^T (x16, A = V frag, B = P register-direct)
#pragma unroll
    for (int kpair = 0; kpair < 2; kpair++)
#pragma unroll
      for (int dvblk = 0; dvblk < 4; dvblk++) {
        const s16x8 vv = *(const s16x8*)&Vs[cur][(dvblk * 2 + kpair) * 512 + lane * 8];
        const s16x4 vlo = {vv[0], vv[1], vv[2], vv[3]};
        const s16x4 vhi = {vv[4], vv[5], vv[6], vv[7]};
#pragma unroll
        for (int qf = 0; qf < 2; qf++) {
          o[qf][dvblk] = MFMA16K16(vlo, pb[qf][kpair * 2 + 0], o[qf][dvblk]);
          o[qf][dvblk] = MFMA16K16(vhi, pb[qf][kpair * 2 + 1], o[qf][dvblk]);
        }
      }
  }

#pragma unroll
  for (int qf = 0; qf < 2; qf++) {
    const float inv = 1.f / lacc[qf][0];   // MFMA l is already cross-lane-complete
    const size_t row = (size_t)(b * Sn + q0 + wave * 32 + qf * 16 + l15);
#pragma unroll
    for (int dvblk = 0; dvblk < 4; dvblk++) {
      u16x4 ov;
#pragma unroll
      for (int r = 0; r < 4; r++) ov[r] = f2bf(o[qf][dvblk][r] * inv);
      *(u16x4*)&ctx[row * Hn + h * 64 + dvblk * 16 + quad * 4] = ov;
    }
  }
}

// ---------------- LayerNorm + residual ----------------
__global__ __launch_bounds__(256)
void ln_res(const float* __restrict__ hid, const float* __restrict__ query,
            const float* __restrict__ gamma, const float* __restrict__ beta,
            float* __restrict__ out)
{
  const int row = blockIdx.x, t = threadIdx.x;
  const f32x4 h = *(const f32x4*)(hid + (size_t)row * Hn + t * 4);
  float s = h[0] + h[1] + h[2] + h[3];
  float ss = h[0]*h[0] + h[1]*h[1] + h[2]*h[2] + h[3]*h[3];
#pragma unroll
  for (int m = 32; m; m >>= 1) { s += __shfl_xor(s, m); ss += __shfl_xor(ss, m); }
  __shared__ float red[8];
  if ((t & 63) == 0) { red[t >> 6] = s; red[4 + (t >> 6)] = ss; }
  __syncthreads();
  s = red[0] + red[1] + red[2] + red[3];
  ss = red[4] + red[5] + red[6] + red[7];
  const float mu = s * (1.f / Hn);
  const float rs = rsqrtf(ss * (1.f / Hn) - mu * mu + 1e-12f);
  const f32x4 q = *(const f32x4*)(query + (size_t)row * Hn + t * 4);
  const f32x4 g = *(const f32x4*)(gamma + t * 4);
  const f32x4 be = *(const f32x4*)(beta + t * 4);
  f32x4 o;
#pragma unroll
  for (int j = 0; j < 4; j++) o[j] = (h[j] - mu) * rs * g[j] + be[j] + q[j];
  *(f32x4*)(out + (size_t)row * Hn + t * 4) = o;
}

extern "C" void kernel_launch(void* const* d_in, const int* in_sizes, int n_in,
                              void* d_out, int out_size, void* d_ws, size_t ws_size,
                              hipStream_t stream) {
  const float* query = (const float*)d_in[0];
  const float* mask  = (const float*)d_in[1];
  const float* Wq = (const float*)d_in[2];
  const float* bq = (const float*)d_in[3];
  const float* Wk = (const float*)d_in[4];
  const float* bk = (const float*)d_in[5];
  const float* Wv = (const float*)d_in[6];
  const float* bv = (const float*)d_in[7];
  const float* Wd = (const float*)d_in[8];
  const float* bd = (const float*)d_in[9];
  const float* gamma = (const float*)d_in[10];
  const float* beta  = (const float*)d_in[11];

  char* w = (char*)d_ws;
  bf_t* Xb  = (bf_t*)w;  w += (size_t)Mn * Hn * 2;        // 16 MB
  bf_t* Wt  = (bf_t*)w;  w += (size_t)3 * Hn * Hn * 2;    // 6 MB  (Wq^T|Wk^T|Wv^T)
  bf_t* Wdt = (bf_t*)w;  w += (size_t)Hn * Hn * 2;        // 2 MB
  bf_t* QKV = (bf_t*)w;  w += (size_t)Mn * 3 * Hn * 2;    // 48 MB
  bf_t* Vf  = (bf_t*)w;  w += (size_t)64 * 32 * 4096 * 2; // 16 MB
  bf_t* Ctx = (bf_t*)w;  w += (size_t)Mn * Hn * 2;        // 16 MB
  // Kf aliases the Hid region: Kf consumed by attn before out-gemm writes Hid
  bf_t* Kf  = (bf_t*)w;                                    // 16 MB (within Hid's 32 MB)
  float* Hid = (float*)w;  w += (size_t)Mn * Hn * 4;       // 32 MB
  float* Mask2 = (float*)w;                                // 32 KB

  prep<<<dim3(32, 32, 5), dim3(32, 8), 0, stream>>>(Wq, Wk, Wv, Wd, query, Wt, Wdt, Xb);
  gemm_bt<<<dim3(24, 64), 256, 0, stream>>>(Xb, Wt, bq, bk, bv, QKV, 3072, 1024, 1);
  kvswz<<<dim3(32, 64, 2), 256, 0, stream>>>(QKV, Kf, Vf, mask, Mask2);
  attn<<<1024, 256, 0, stream>>>(QKV, Kf, Vf, Mask2, Ctx);
  gemm_bt<<<dim3(8, 64), 256, 0, stream>>>(Ctx, Wdt, bd, bd, bd, Hid, 1024, 1024, 0);
  ln_res<<<Mn, 256, 0, stream>>>(Hid, query, gamma, beta, (float*)d_out);
}